// Round 1
// baseline (2357.708 us; speedup 1.0000x reference)
//
#include <hip/hip_runtime.h>
#include <hip/hip_bf16.h>

#define CC 64
#define HIDN 128
#define DCC 16
#define HH 128
#define WW 128
#define HWS (HH*WW)        // 16384
#define BB 16
#define NPIX (BB*HWS)      // 262144

typedef __hip_bfloat16 bf16;

__device__ __forceinline__ float rcp_fast(float x){ return __builtin_amdgcn_rcpf(x); }
__device__ __forceinline__ float ftanh(float x){
    float e = __expf(2.f*x);
    return 1.f - 2.f*rcp_fast(e + 1.f);
}
__device__ __forceinline__ float fsig(float x){
    return rcp_fast(1.f + __expf(-x));
}
// tanh-form gelu rewritten as x * sigmoid(2u), u = 0.79788456(x + 0.044715 x^3)
__device__ __forceinline__ float fgelu(float x){
    return x * fsig(x*(1.5957691216f + 0.07135481283f*x*x));
}
__device__ __forceinline__ float b2f(bf16 v){ return __bfloat162float(v); }
__device__ __forceinline__ bf16  f2b(float v){ return __float2bfloat16(v); }

// ---------------------------------------------------------------- convert
__global__ __launch_bounds__(256) void k_convert(const float* __restrict__ in,
                                                 bf16* __restrict__ out, int n){
    int i = blockIdx.x*256 + threadIdx.x;
    if (i < n) out[i] = f2b(in[i]);
}

// ---------------------------------------------------------------- gate
// per 64-pixel tile: t1=tanh(Wz1 x+b); Z=tanh(Wz2 t1+b); t2=tanh(Wf1 x+b);
// F=sigmoid(Wf2 t2+b); v=(1-F)*Z
__device__ __forceinline__ void mmtile(const float (&src)[CC][64],
    const float* __restrict__ w, int ob, int p, float acc[16])
{
    #pragma unroll
    for (int j=0;j<16;++j) acc[j] = 0.f;
    #pragma unroll 4
    for (int c=0;c<CC;++c){
        float xv = src[c][p];
        #pragma unroll
        for (int j=0;j<16;++j)
            acc[j] = fmaf(w[(ob+j)*CC + c], xv, acc[j]);
    }
}

__global__ __launch_bounds__(256) void k_gate(
    const bf16* __restrict__ xin,
    const float* __restrict__ wz1, const float* __restrict__ bz1,
    const float* __restrict__ wz2, const float* __restrict__ bz2,
    const float* __restrict__ wf1, const float* __restrict__ bf1,
    const float* __restrict__ wf2, const float* __restrict__ bf2,
    bf16* __restrict__ vout)
{
    __shared__ float xs[CC][64];
    __shared__ float ts[CC][64];
    const int t = threadIdx.x;
    const int p = t & 63;
    const int ob = __builtin_amdgcn_readfirstlane((t >> 6) << 4);
    const int pix0 = blockIdx.x << 6;
    const int b = pix0 >> 14;
    const int sp = (pix0 & (HWS-1)) + p;
    const bf16* xb = xin + (size_t)b*CC*HWS + sp;
    #pragma unroll
    for (int j = 0; j < 16; ++j)
        xs[ob + j][p] = b2f(xb[(size_t)(ob + j) * HWS]);
    __syncthreads();

    float tmp[16], zz[16];
    mmtile(xs, wz1, ob, p, tmp);
    #pragma unroll
    for (int j=0;j<16;++j) ts[ob+j][p] = ftanh(tmp[j] + bz1[ob+j]);
    __syncthreads();
    mmtile(ts, wz2, ob, p, tmp);
    #pragma unroll
    for (int j=0;j<16;++j) zz[j] = ftanh(tmp[j] + bz2[ob+j]);
    __syncthreads();                       // everyone done reading ts
    mmtile(xs, wf1, ob, p, tmp);
    #pragma unroll
    for (int j=0;j<16;++j) ts[ob+j][p] = ftanh(tmp[j] + bf1[ob+j]);
    __syncthreads();
    mmtile(ts, wf2, ob, p, tmp);
    bf16* vb = vout + (size_t)b*CC*HWS + sp;
    #pragma unroll
    for (int j=0;j<16;++j){
        float F = fsig(tmp[j] + bf2[ob+j]);
        vb[(size_t)(ob+j)*HWS] = f2b((1.f - F) * zz[j]);
    }
}

// ---------------------------------------------------------------- pconv (16->16, 3x3, dense)
__global__ __launch_bounds__(256) void k_pconv(
    const bf16* __restrict__ v, const float* __restrict__ w, bf16* __restrict__ x1)
{
    int gid = blockIdx.x*256 + threadIdx.x;
    int b = gid >> 14;
    int sp = gid & (HWS-1);
    int y = sp >> 7, x = sp & 127;
    const bf16* vb = v + (size_t)b*CC*HWS;
    float acc[DCC];
    #pragma unroll
    for (int o=0;o<DCC;++o) acc[o] = 0.f;
    #pragma unroll 1
    for (int ic=0; ic<DCC; ++ic){
        float xv[9];
        #pragma unroll
        for (int ky=0;ky<3;++ky){
            int yy = y + ky - 1;
            bool oky = (yy>=0) & (yy<HH);
            #pragma unroll
            for (int kx=0;kx<3;++kx){
                int xx = x + kx - 1;
                bool ok = oky & (xx>=0) & (xx<WW);
                xv[ky*3+kx] = ok ? b2f(vb[(size_t)ic*HWS + yy*WW + xx]) : 0.f;
            }
        }
        #pragma unroll
        for (int o=0;o<DCC;++o){
            #pragma unroll
            for (int k=0;k<9;++k)
                acc[o] = fmaf(w[(o*DCC+ic)*9 + k], xv[k], acc[o]);
        }
    }
    bf16* xo = x1 + (size_t)b*DCC*HWS + sp;
    #pragma unroll
    for (int o=0;o<DCC;++o) xo[(size_t)o*HWS] = f2b(acc[o]);
}

// ---------------------------------------------------------------- lin1 (64->256 + gelu)
__global__ __launch_bounds__(256) void k_lin1(
    const bf16* __restrict__ x1, const bf16* __restrict__ v,
    const float* __restrict__ w, const float* __restrict__ bias,
    bf16* __restrict__ h)
{
    __shared__ float us[CC][64];
    const int t = threadIdx.x;
    const int p = t & 63;
    const int cb = __builtin_amdgcn_readfirstlane((t>>6) << 4);
    const int pix0 = blockIdx.x << 6;
    const int b = pix0 >> 14;
    const int sp = (pix0 & (HWS-1)) + p;
    #pragma unroll
    for (int j=0;j<16;++j){
        int c = cb + j;
        float val;
        if (c < DCC) val = b2f(x1[((size_t)b*DCC + c)*HWS + sp]);
        else         val = b2f(v [((size_t)b*CC  + c)*HWS + sp]);
        us[c][p] = val;
    }
    __syncthreads();
    const int ob = __builtin_amdgcn_readfirstlane((t>>6) << 6);
    float acc[64];
    #pragma unroll
    for (int j=0;j<64;++j) acc[j] = 0.f;
    #pragma unroll 2
    for (int c=0;c<CC;++c){
        float xv = us[c][p];
        #pragma unroll
        for (int j=0;j<64;++j)
            acc[j] = fmaf(w[c*256 + ob + j], xv, acc[j]);
    }
    bf16* hb = h + (size_t)b*256*HWS + sp;
    #pragma unroll
    for (int j=0;j<64;++j)
        hb[(size_t)(ob+j)*HWS] = f2b(fgelu(acc[j] + bias[ob+j]));
}

// ---------------------------------------------------------------- dw conv + gate + lin2 + residual
__global__ __launch_bounds__(256) void k_dwmul(
    const bf16* __restrict__ h,
    const float* __restrict__ dww, const float* __restrict__ dwb,
    const float* __restrict__ w2, const float* __restrict__ b2v,
    const bf16* __restrict__ v,
    bf16* __restrict__ xout,
    const float* __restrict__ xinit,   // non-null on last layer
    bf16* __restrict__ xsum)           // may alias v
{
    __shared__ float gs[HIDN][64];     // 32 KB
    const int t = threadIdx.x;
    const int p = t & 63;
    const int pix0 = blockIdx.x << 6;
    const int b = pix0 >> 14;
    const int sp0 = pix0 & (HWS-1);
    const int sp = sp0 + p;
    const int y = sp0 >> 7;
    const int x = (sp0 & 127) + p;
    const bf16* hb = h + (size_t)b*(2*HIDN)*HWS;
    const int kb = __builtin_amdgcn_readfirstlane((t>>6) << 5);
    #pragma unroll 1
    for (int j=0;j<32;++j){
        int k = kb + j;
        const bf16* hk = hb + (size_t)k*HWS;
        float acc = 0.f;
        #pragma unroll
        for (int ky=0;ky<3;++ky){
            int yy = y + ky - 1;
            bool oky = (yy>=0) & (yy<HH);
            #pragma unroll
            for (int kx=0;kx<3;++kx){
                int xx = x + kx - 1;
                bool ok = oky & (xx>=0) & (xx<WW);
                float hv = ok ? b2f(hk[yy*WW + xx]) : 0.f;
                acc = fmaf(dww[k*9 + ky*3 + kx], hv, acc);
            }
        }
        float h1 = fgelu(acc + dwb[k]);
        float h2 = b2f(hb[(size_t)(HIDN + k)*HWS + sp]);
        gs[k][p] = h1 * h2;
    }
    __syncthreads();
    const int ob = __builtin_amdgcn_readfirstlane((t>>6) << 4);
    float acc[16];
    #pragma unroll
    for (int j=0;j<16;++j) acc[j] = 0.f;
    #pragma unroll 2
    for (int kk=0;kk<HIDN;++kk){
        float gv = gs[kk][p];
        #pragma unroll
        for (int j=0;j<16;++j)
            acc[j] = fmaf(w2[kk*CC + ob + j], gv, acc[j]);
    }
    bf16* xo = xout + (size_t)b*CC*HWS + sp;
    const bf16* vb = v + (size_t)b*CC*HWS + sp;
    #pragma unroll
    for (int j=0;j<16;++j){
        float r = acc[j] + b2v[ob+j] + b2f(vb[(size_t)(ob+j)*HWS]);
        xo[(size_t)(ob+j)*HWS] = f2b(r);
        if (xinit){
            float s = r + xinit[((size_t)b*CC + ob + j)*HWS + sp];
            xsum[(size_t)b*CC*HWS + (size_t)(ob+j)*HWS + sp] = f2b(s);
        }
    }
}

// ---------------------------------------------------------------- final conv (64->1, 3x3)
__global__ __launch_bounds__(256) void k_final(
    const bf16* __restrict__ s, const float* __restrict__ w,
    const float* __restrict__ bias, float* __restrict__ out)
{
    int gid = blockIdx.x*256 + threadIdx.x;
    int b = gid >> 14;
    int sp = gid & (HWS-1);
    int y = sp >> 7, x = sp & 127;
    const bf16* sb = s + (size_t)b*CC*HWS;
    float acc = bias[0];
    #pragma unroll 1
    for (int c=0;c<CC;++c){
        #pragma unroll
        for (int ky=0;ky<3;++ky){
            int yy = y + ky - 1;
            bool oky = (yy>=0) & (yy<HH);
            #pragma unroll
            for (int kx=0;kx<3;++kx){
                int xx = x + kx - 1;
                bool ok = oky & (xx>=0) & (xx<WW);
                float sv = ok ? b2f(sb[(size_t)c*HWS + yy*WW + xx]) : 0.f;
                acc = fmaf(w[c*9 + ky*3 + kx], sv, acc);
            }
        }
    }
    out[gid] = acc;
}

// ---------------------------------------------------------------- launch
extern "C" void kernel_launch(void* const* d_in, const int* in_sizes, int n_in,
                              void* d_out, int out_size, void* d_ws, size_t ws_size,
                              hipStream_t stream)
{
    const float* x    = (const float*)d_in[0];
    const float* wz1  = (const float*)d_in[1];
    const float* bz1  = (const float*)d_in[2];
    const float* wz2  = (const float*)d_in[3];
    const float* bz2  = (const float*)d_in[4];
    const float* wf1  = (const float*)d_in[5];
    const float* bf1  = (const float*)d_in[6];
    const float* wf2  = (const float*)d_in[7];
    const float* bf2  = (const float*)d_in[8];
    const float* pw   = (const float*)d_in[9];
    const float* l1w  = (const float*)d_in[10];
    const float* l1b  = (const float*)d_in[11];
    const float* dww  = (const float*)d_in[12];
    const float* dwb  = (const float*)d_in[13];
    const float* l2w  = (const float*)d_in[14];
    const float* l2b  = (const float*)d_in[15];
    const float* ow   = (const float*)d_in[16];
    const float* obb  = (const float*)d_in[17];

    char* ws = (char*)d_ws;
    bf16* xc = (bf16*)(ws);                       // 33,554,432 B
    bf16* v  = (bf16*)(ws + 33554432);            // 33,554,432 B
    bf16* x1 = (bf16*)(ws + 67108864);            //  8,388,608 B
    bf16* h  = (bf16*)(ws + 75497472);            // 134,217,728 B  (total ~210 MB)

    k_convert<<<(NPIX*CC)/256, 256, 0, stream>>>(x, xc, NPIX*CC);
    for (int l=0;l<3;++l){
        k_gate <<<NPIX/64, 256, 0, stream>>>(xc,
                wz1 + l*CC*CC, bz1 + l*CC, wz2 + l*CC*CC, bz2 + l*CC,
                wf1 + l*CC*CC, bf1 + l*CC, wf2 + l*CC*CC, bf2 + l*CC, v);
        k_pconv<<<NPIX/256, 256, 0, stream>>>(v, pw + l*DCC*DCC*9, x1);
        k_lin1 <<<NPIX/64, 256, 0, stream>>>(x1, v, l1w + l*CC*256, l1b + l*256, h);
        k_dwmul<<<NPIX/64, 256, 0, stream>>>(h, dww + l*HIDN*9, dwb + l*HIDN,
                l2w + l*HIDN*CC, l2b + l*CC, v, xc,
                (l==2) ? x : nullptr, v);
    }
    k_final<<<NPIX/256, 256, 0, stream>>>(v, ow, obb, (float*)d_out);
}

// Round 2
// 1513.699 us; speedup vs baseline: 1.5576x; 1.5576x over previous
//
#include <hip/hip_runtime.h>
#include <hip/hip_bf16.h>

#define CC 64
#define HIDN 128
#define DCC 16
#define HH 128
#define WW 128
#define HWS (HH*WW)        // 16384
#define BB 16
#define NPIX (BB*HWS)      // 262144

typedef __hip_bfloat16 bf16;
typedef __attribute__((ext_vector_type(8))) unsigned short ushort8;
typedef __attribute__((ext_vector_type(4))) unsigned short ushort4v;
typedef __attribute__((ext_vector_type(4))) float float4v;

__device__ __forceinline__ float rcp_fast(float x){ return __builtin_amdgcn_rcpf(x); }
__device__ __forceinline__ float ftanh(float x){
    float e = __expf(2.f*x);
    return 1.f - 2.f*rcp_fast(e + 1.f);
}
__device__ __forceinline__ float fsig(float x){
    return rcp_fast(1.f + __expf(-x));
}
__device__ __forceinline__ float fgelu(float x){
    return x * fsig(x*(1.5957691216f + 0.07135481283f*x*x));
}
__device__ __forceinline__ float b2f(bf16 v){ return __bfloat162float(v); }
__device__ __forceinline__ bf16  f2b(float v){ return __float2bfloat16(v); }
__device__ __forceinline__ float u2f(unsigned short u){
    unsigned v = ((unsigned)u) << 16; return __uint_as_float(v);
}
__device__ __forceinline__ unsigned short f2u(float f){
    bf16 h = __float2bfloat16(f);
    return *reinterpret_cast<unsigned short*>(&h);
}

// ---------------------------------------------------------------- convert (8 elems/thread)
__global__ __launch_bounds__(256) void k_convert(const float* __restrict__ in,
                                                 bf16* __restrict__ out, int n){
    int i = (blockIdx.x*256 + threadIdx.x) * 8;
    if (i >= n) return;
    const float4v* ip = reinterpret_cast<const float4v*>(in + i);
    float4v a = ip[0], b = ip[1];
    ushort8 o;
    o[0]=f2u(a.x); o[1]=f2u(a.y); o[2]=f2u(a.z); o[3]=f2u(a.w);
    o[4]=f2u(b.x); o[5]=f2u(b.y); o[6]=f2u(b.z); o[7]=f2u(b.w);
    *reinterpret_cast<ushort8*>(out + i) = o;
}

// ---------------------------------------------------------------- gate
__device__ __forceinline__ void mmtile(const float (&src)[CC][64],
    const float* __restrict__ w, int ob, int p, float acc[16])
{
    #pragma unroll
    for (int j=0;j<16;++j) acc[j] = 0.f;
    #pragma unroll 4
    for (int c=0;c<CC;++c){
        float xv = src[c][p];
        #pragma unroll
        for (int j=0;j<16;++j)
            acc[j] = fmaf(w[(ob+j)*CC + c], xv, acc[j]);
    }
}

__global__ __launch_bounds__(256) void k_gate(
    const bf16* __restrict__ xin,
    const float* __restrict__ wz1, const float* __restrict__ bz1,
    const float* __restrict__ wz2, const float* __restrict__ bz2,
    const float* __restrict__ wf1, const float* __restrict__ bf1,
    const float* __restrict__ wf2, const float* __restrict__ bf2,
    bf16* __restrict__ vout)
{
    __shared__ float xs[CC][64];
    __shared__ float ts[CC][64];
    const int t = threadIdx.x;
    const int p = t & 63;
    const int ob = __builtin_amdgcn_readfirstlane((t >> 6) << 4);
    const int pix0 = blockIdx.x << 6;
    const int b = pix0 >> 14;
    const int sp = (pix0 & (HWS-1)) + p;
    const bf16* xb = xin + (size_t)b*CC*HWS + sp;
    #pragma unroll
    for (int j = 0; j < 16; ++j)
        xs[ob + j][p] = b2f(xb[(size_t)(ob + j) * HWS]);
    __syncthreads();

    float tmp[16], zz[16];
    mmtile(xs, wz1, ob, p, tmp);
    #pragma unroll
    for (int j=0;j<16;++j) ts[ob+j][p] = ftanh(tmp[j] + bz1[ob+j]);
    __syncthreads();
    mmtile(ts, wz2, ob, p, tmp);
    #pragma unroll
    for (int j=0;j<16;++j) zz[j] = ftanh(tmp[j] + bz2[ob+j]);
    __syncthreads();
    mmtile(xs, wf1, ob, p, tmp);
    #pragma unroll
    for (int j=0;j<16;++j) ts[ob+j][p] = ftanh(tmp[j] + bf1[ob+j]);
    __syncthreads();
    mmtile(ts, wf2, ob, p, tmp);
    bf16* vb = vout + (size_t)b*CC*HWS + sp;
    #pragma unroll
    for (int j=0;j<16;++j){
        float F = fsig(tmp[j] + bf2[ob+j]);
        vb[(size_t)(ob+j)*HWS] = f2b((1.f - F) * zz[j]);
    }
}

// ---------------------------------------------------------------- pconv (16->16, 3x3), 4 px/thread
__global__ __launch_bounds__(256) void k_pconv(
    const bf16* __restrict__ v, const float* __restrict__ w, bf16* __restrict__ x1)
{
    int gid = blockIdx.x*256 + threadIdx.x;       // thread = 4 px
    int b = gid >> 12;
    int sp4 = (gid & 4095) << 2;
    int y = sp4 >> 7, x0 = sp4 & 127;
    const bf16* vb = v + (size_t)b*CC*HWS;
    float acc[DCC][4];
    #pragma unroll
    for (int o=0;o<DCC;++o)
        #pragma unroll
        for (int i=0;i<4;++i) acc[o][i] = 0.f;

    #pragma unroll 1
    for (int ic=0; ic<DCC; ++ic){
        const bf16* ip = vb + (size_t)ic*HWS;
        float xv[3][6];
        #pragma unroll
        for (int ky=0;ky<3;++ky){
            int yy = y + ky - 1;
            if (yy >= 0 && yy < HH){
                const bf16* rp = ip + yy*WW + x0;
                ushort4v mv = *reinterpret_cast<const ushort4v*>(rp);
                xv[ky][1]=u2f(mv[0]); xv[ky][2]=u2f(mv[1]);
                xv[ky][3]=u2f(mv[2]); xv[ky][4]=u2f(mv[3]);
                xv[ky][0] = (x0>0)     ? b2f(rp[-1]) : 0.f;
                xv[ky][5] = (x0+4<WW)  ? b2f(rp[4])  : 0.f;
            } else {
                #pragma unroll
                for (int i=0;i<6;++i) xv[ky][i] = 0.f;
            }
        }
        #pragma unroll
        for (int o=0;o<DCC;++o){
            const float* wp = w + (size_t)(o*DCC+ic)*9;
            #pragma unroll
            for (int ky=0;ky<3;++ky){
                float w0 = wp[ky*3+0], w1 = wp[ky*3+1], w2 = wp[ky*3+2];
                #pragma unroll
                for (int i=0;i<4;++i)
                    acc[o][i] = fmaf(w0, xv[ky][i],
                                fmaf(w1, xv[ky][i+1],
                                fmaf(w2, xv[ky][i+2], acc[o][i])));
            }
        }
    }
    bf16* xo = x1 + (size_t)b*DCC*HWS + sp4;
    #pragma unroll
    for (int o=0;o<DCC;++o){
        ushort4v ov;
        #pragma unroll
        for (int i=0;i<4;++i) ov[i] = f2u(acc[o][i]);
        *reinterpret_cast<ushort4v*>(xo + (size_t)o*HWS) = ov;
    }
}

// ---------------------------------------------------------------- lin1 (64->256 + gelu)
__global__ __launch_bounds__(256) void k_lin1(
    const bf16* __restrict__ x1, const bf16* __restrict__ v,
    const float* __restrict__ w, const float* __restrict__ bias,
    bf16* __restrict__ h)
{
    __shared__ float us[CC][64];
    const int t = threadIdx.x;
    const int p = t & 63;
    const int cb = __builtin_amdgcn_readfirstlane((t>>6) << 4);
    const int pix0 = blockIdx.x << 6;
    const int b = pix0 >> 14;
    const int sp = (pix0 & (HWS-1)) + p;
    #pragma unroll
    for (int j=0;j<16;++j){
        int c = cb + j;
        float val;
        if (c < DCC) val = b2f(x1[((size_t)b*DCC + c)*HWS + sp]);
        else         val = b2f(v [((size_t)b*CC  + c)*HWS + sp]);
        us[c][p] = val;
    }
    __syncthreads();
    const int ob = __builtin_amdgcn_readfirstlane((t>>6) << 6);
    float acc[64];
    #pragma unroll
    for (int j=0;j<64;++j) acc[j] = 0.f;
    #pragma unroll 2
    for (int c=0;c<CC;++c){
        float xv = us[c][p];
        #pragma unroll
        for (int j=0;j<64;++j)
            acc[j] = fmaf(w[c*256 + ob + j], xv, acc[j]);
    }
    bf16* hb = h + (size_t)b*256*HWS + sp;
    #pragma unroll
    for (int j=0;j<64;++j)
        hb[(size_t)(ob+j)*HWS] = f2b(fgelu(acc[j] + bias[ob+j]));
}

// ---------------------------------------------------------------- dw conv + gelu + gate -> g (in-place over h2)
// NOTE: h and gout alias (gout == h); each g element is read (as h2) and
// written only by the same thread. h1 planes (0..127) are never written.
__global__ __launch_bounds__(256) void k_dwgate(
    const bf16* h, const float* __restrict__ dww,
    const float* __restrict__ dwb, bf16* gout)
{
    const int t   = threadIdx.x;
    const int bid = blockIdx.x;
    const int rg  = bid & 7;
    const int k   = __builtin_amdgcn_readfirstlane((bid >> 3) & 127);
    const int b   = __builtin_amdgcn_readfirstlane(bid >> 10);
    const int row = (rg << 4) + (t >> 4);
    const int x0  = (t & 15) << 3;

    const bf16* h1p = h + ((size_t)(b*256 + k))*HWS;
    float acc[8];
    #pragma unroll
    for (int i=0;i<8;++i) acc[i]=0.f;

    #pragma unroll
    for (int ky=0; ky<3; ++ky){
        int yy = row + ky - 1;
        if (yy < 0 || yy >= HH) continue;
        const bf16* rp = h1p + yy*WW + x0;
        ushort8 mv = *reinterpret_cast<const ushort8*>(rp);
        float m[8];
        #pragma unroll
        for (int i=0;i<8;++i) m[i] = u2f(mv[i]);
        float lft = (x0>0)    ? b2f(rp[-1]) : 0.f;
        float rgt = (x0+8<WW) ? b2f(rp[8])  : 0.f;
        float w0 = dww[k*9+ky*3+0], w1 = dww[k*9+ky*3+1], w2 = dww[k*9+ky*3+2];
        #pragma unroll
        for (int i=0;i<8;++i){
            float l = (i==0) ? lft : m[i-1];
            float r = (i==7) ? rgt : m[i+1];
            acc[i] = fmaf(w0, l, fmaf(w1, m[i], fmaf(w2, r, acc[i])));
        }
    }
    float bk = dwb[k];
    const size_t off2 = ((size_t)(b*256 + 128 + k))*HWS + row*WW + x0;
    ushort8 h2v = *reinterpret_cast<const ushort8*>(h + off2);
    ushort8 ov;
    #pragma unroll
    for (int i=0;i<8;++i){
        float h1 = fgelu(acc[i] + bk);
        ov[i] = f2u(h1 * u2f(h2v[i]));
    }
    *reinterpret_cast<ushort8*>(gout + off2) = ov;
}

// ---------------------------------------------------------------- lin2 (128->64) + residual
__global__ __launch_bounds__(256) void k_lin2(
    const bf16* __restrict__ hg,     // g lives in planes 128..255 of h
    const float* __restrict__ w2, const float* __restrict__ b2v,
    const bf16* __restrict__ v,
    bf16* __restrict__ xout,
    const float* __restrict__ xinit,   // non-null on last layer
    bf16* __restrict__ xsum)           // may alias v
{
    __shared__ float gs[HIDN][64];     // 32 KB
    const int t = threadIdx.x;
    const int p = t & 63;
    const int pix0 = blockIdx.x << 6;
    const int b = pix0 >> 14;
    const int sp = (pix0 & (HWS-1)) + p;
    const int cb = __builtin_amdgcn_readfirstlane((t>>6) << 5);
    const bf16* gb = hg + (size_t)(b*256 + 128)*HWS + sp;
    #pragma unroll
    for (int j=0;j<32;++j){
        int c = cb + j;
        gs[c][p] = b2f(gb[(size_t)c*HWS]);
    }
    __syncthreads();
    const int ob = __builtin_amdgcn_readfirstlane((t>>6) << 4);
    float acc[16];
    #pragma unroll
    for (int j=0;j<16;++j) acc[j] = 0.f;
    #pragma unroll 2
    for (int kk=0;kk<HIDN;++kk){
        float gv = gs[kk][p];
        #pragma unroll
        for (int j=0;j<16;++j)
            acc[j] = fmaf(w2[kk*CC + ob + j], gv, acc[j]);
    }
    bf16* xo = xout + (size_t)b*CC*HWS + sp;
    const bf16* vb = v + (size_t)b*CC*HWS + sp;
    #pragma unroll
    for (int j=0;j<16;++j){
        float r = acc[j] + b2v[ob+j] + b2f(vb[(size_t)(ob+j)*HWS]);
        xo[(size_t)(ob+j)*HWS] = f2b(r);
        if (xinit){
            float s = r + xinit[((size_t)b*CC + ob + j)*HWS + sp];
            xsum[(size_t)b*CC*HWS + (size_t)(ob+j)*HWS + sp] = f2b(s);
        }
    }
}

// ---------------------------------------------------------------- final conv (64->1, 3x3), 4 px/thread
__global__ __launch_bounds__(256) void k_final(
    const bf16* __restrict__ s, const float* __restrict__ w,
    const float* __restrict__ bias, float* __restrict__ out)
{
    int gid = blockIdx.x*256 + threadIdx.x;   // thread = 4 px
    int b = gid >> 12;
    int sp4 = (gid & 4095) << 2;
    int y = sp4 >> 7, x0 = sp4 & 127;
    const bf16* sb = s + (size_t)b*CC*HWS;
    float acc[4];
    #pragma unroll
    for (int i=0;i<4;++i) acc[i] = bias[0];

    #pragma unroll 1
    for (int c=0;c<CC;++c){
        const bf16* ip = sb + (size_t)c*HWS;
        const float* wp = w + (size_t)c*9;
        #pragma unroll
        for (int ky=0;ky<3;++ky){
            int yy = y + ky - 1;
            float xv[6];
            if (yy >= 0 && yy < HH){
                const bf16* rp = ip + yy*WW + x0;
                ushort4v mv = *reinterpret_cast<const ushort4v*>(rp);
                xv[1]=u2f(mv[0]); xv[2]=u2f(mv[1]); xv[3]=u2f(mv[2]); xv[4]=u2f(mv[3]);
                xv[0] = (x0>0)    ? b2f(rp[-1]) : 0.f;
                xv[5] = (x0+4<WW) ? b2f(rp[4])  : 0.f;
            } else {
                #pragma unroll
                for (int i=0;i<6;++i) xv[i] = 0.f;
            }
            float w0 = wp[ky*3+0], w1 = wp[ky*3+1], w2 = wp[ky*3+2];
            #pragma unroll
            for (int i=0;i<4;++i)
                acc[i] = fmaf(w0, xv[i],
                         fmaf(w1, xv[i+1],
                         fmaf(w2, xv[i+2], acc[i])));
        }
    }
    float4v ov; ov.x=acc[0]; ov.y=acc[1]; ov.z=acc[2]; ov.w=acc[3];
    *reinterpret_cast<float4v*>(out + (size_t)gid*4) = ov;
}

// ---------------------------------------------------------------- launch
extern "C" void kernel_launch(void* const* d_in, const int* in_sizes, int n_in,
                              void* d_out, int out_size, void* d_ws, size_t ws_size,
                              hipStream_t stream)
{
    const float* x    = (const float*)d_in[0];
    const float* wz1  = (const float*)d_in[1];
    const float* bz1  = (const float*)d_in[2];
    const float* wz2  = (const float*)d_in[3];
    const float* bz2  = (const float*)d_in[4];
    const float* wf1  = (const float*)d_in[5];
    const float* bf1  = (const float*)d_in[6];
    const float* wf2  = (const float*)d_in[7];
    const float* bf2  = (const float*)d_in[8];
    const float* pw   = (const float*)d_in[9];
    const float* l1w  = (const float*)d_in[10];
    const float* l1b  = (const float*)d_in[11];
    const float* dww  = (const float*)d_in[12];
    const float* dwb  = (const float*)d_in[13];
    const float* l2w  = (const float*)d_in[14];
    const float* l2b  = (const float*)d_in[15];
    const float* ow   = (const float*)d_in[16];
    const float* obb  = (const float*)d_in[17];

    char* ws = (char*)d_ws;
    bf16* xc = (bf16*)(ws);                       // 33,554,432 B
    bf16* v  = (bf16*)(ws + 33554432);            // 33,554,432 B
    bf16* x1 = (bf16*)(ws + 67108864);            //  8,388,608 B
    bf16* h  = (bf16*)(ws + 75497472);            // 134,217,728 B (g aliases planes 128..255)

    k_convert<<<(NPIX*CC)/(256*8), 256, 0, stream>>>(x, xc, NPIX*CC);
    for (int l=0;l<3;++l){
        k_gate <<<NPIX/64, 256, 0, stream>>>(xc,
                wz1 + l*CC*CC, bz1 + l*CC, wz2 + l*CC*CC, bz2 + l*CC,
                wf1 + l*CC*CC, bf1 + l*CC, wf2 + l*CC*CC, bf2 + l*CC, v);
        k_pconv<<<NPIX/(256*4), 256, 0, stream>>>(v, pw + l*DCC*DCC*9, x1);
        k_lin1 <<<NPIX/64, 256, 0, stream>>>(x1, v, l1w + l*CC*256, l1b + l*256, h);
        k_dwgate<<<BB*HIDN*(HH/16), 256, 0, stream>>>(h, dww + l*HIDN*9, dwb + l*HIDN, h);
        k_lin2 <<<NPIX/64, 256, 0, stream>>>(h, l2w + l*HIDN*CC, l2b + l*CC, v, xc,
                (l==2) ? x : nullptr, v);
    }
    k_final<<<NPIX/(256*4), 256, 0, stream>>>(v, ow, obb, (float*)d_out);
}

// Round 3
// 1046.619 us; speedup vs baseline: 2.2527x; 1.4463x over previous
//
#include <hip/hip_runtime.h>
#include <hip/hip_bf16.h>

#define CC 64
#define HIDN 128
#define DCC 16
#define HH 128
#define WW 128
#define HWS (HH*WW)        // 16384
#define BB 16
#define NPIX (BB*HWS)      // 262144

typedef __hip_bfloat16 bf16;
typedef __attribute__((ext_vector_type(8))) unsigned short ushort8;
typedef __attribute__((ext_vector_type(4))) unsigned short ushort4v;
typedef __attribute__((ext_vector_type(4))) float float4v;
typedef __attribute__((ext_vector_type(8))) short bf16x8;
typedef __attribute__((ext_vector_type(4))) float f32x4;

__device__ __forceinline__ float rcp_fast(float x){ return __builtin_amdgcn_rcpf(x); }
__device__ __forceinline__ float ftanh(float x){
    float e = __expf(2.f*x);
    return 1.f - 2.f*rcp_fast(e + 1.f);
}
__device__ __forceinline__ float fsig(float x){
    return rcp_fast(1.f + __expf(-x));
}
__device__ __forceinline__ float fgelu(float x){
    return x * fsig(x*(1.5957691216f + 0.07135481283f*x*x));
}
__device__ __forceinline__ float b2f(bf16 v){ return __bfloat162float(v); }
__device__ __forceinline__ bf16  f2b(float v){ return __float2bfloat16(v); }
__device__ __forceinline__ float u2f(unsigned short u){
    unsigned v = ((unsigned)u) << 16; return __uint_as_float(v);
}
__device__ __forceinline__ unsigned short f2u(float f){
    bf16 h = __float2bfloat16(f);
    return *reinterpret_cast<unsigned short*>(&h);
}
__device__ __forceinline__ bf16x8 packf(float4v a, float4v b){
    bf16x8 r;
    r[0]=(short)f2u(a.x); r[1]=(short)f2u(a.y); r[2]=(short)f2u(a.z); r[3]=(short)f2u(a.w);
    r[4]=(short)f2u(b.x); r[5]=(short)f2u(b.y); r[6]=(short)f2u(b.z); r[7]=(short)f2u(b.w);
    return r;
}

// ---------------------------------------------------------------- convert (8 elems/thread)
__global__ __launch_bounds__(256) void k_convert(const float* __restrict__ in,
                                                 bf16* __restrict__ out, int n){
    int i = (blockIdx.x*256 + threadIdx.x) * 8;
    if (i >= n) return;
    const float4v* ip = reinterpret_cast<const float4v*>(in + i);
    float4v a = ip[0], b = ip[1];
    ushort8 o;
    o[0]=f2u(a.x); o[1]=f2u(a.y); o[2]=f2u(a.z); o[3]=f2u(a.w);
    o[4]=f2u(b.x); o[5]=f2u(b.y); o[6]=f2u(b.z); o[7]=f2u(b.w);
    *reinterpret_cast<ushort8*>(out + i) = o;
}

// ---------------------------------------------------------------- gate (MFMA, zero-shuffle chain)
// per 16-px tile: t1=tanh(Wz1 x+b); Z=tanh(Wz2 t1+b); t2=tanh(Wf1 x+b);
// F=sigmoid(Wf2 t2+b); v=(1-F)*Z
__global__ __launch_bounds__(256,2) void k_gate(
    const bf16* __restrict__ xin,
    const float* __restrict__ wz1, const float* __restrict__ bz1,
    const float* __restrict__ wz2, const float* __restrict__ bz2,
    const float* __restrict__ wf1, const float* __restrict__ bf1,
    const float* __restrict__ wf2, const float* __restrict__ bf2,
    bf16* __restrict__ vout)
{
    const int t = threadIdx.x;
    const int lane = t & 63;
    const int wv = t >> 6;
    const int col = lane & 15;       // px within tile (B/D col) == out-ch row (A)
    const int g = lane >> 4;         // 0..3
    const int blk = blockIdx.x;      // 512 blocks, 512 px each
    const int b = blk >> 5;
    const int sp0 = (blk & 31) << 9;

    // A fragments. Stage-1 slot (g,j) holds W[o][kh*32+g*8+j]  (psi1)
    // Stage-2 slot (g,j) holds W[o][kh*32+(j>>2)*16+g*4+(j&3)] (psi2 = D layout of stage 1)
    bf16x8 Az1[4][2], Af1[4][2], Az2[4][2], Af2[4][2];
    #pragma unroll
    for (int ot=0; ot<4; ++ot){
        #pragma unroll
        for (int kh=0; kh<2; ++kh){
            const float* p;
            p = wz1 + (ot*16+col)*64 + kh*32 + g*8;
            Az1[ot][kh] = packf(*(const float4v*)p, *(const float4v*)(p+4));
            p = wf1 + (ot*16+col)*64 + kh*32 + g*8;
            Af1[ot][kh] = packf(*(const float4v*)p, *(const float4v*)(p+4));
            p = wz2 + (ot*16+col)*64 + kh*32 + g*4;
            Az2[ot][kh] = packf(*(const float4v*)p, *(const float4v*)(p+16));
            p = wf2 + (ot*16+col)*64 + kh*32 + g*4;
            Af2[ot][kh] = packf(*(const float4v*)p, *(const float4v*)(p+16));
        }
    }
    const bf16* xb = xin + (size_t)b*CC*HWS;
    bf16*       vb = vout + (size_t)b*CC*HWS;

    for (int it = wv; it < 32; it += 4){
        const int px = sp0 + it*16 + col;
        bf16x8 Bx[2];
        #pragma unroll
        for (int kh=0; kh<2; ++kh)
            #pragma unroll
            for (int j=0; j<8; ++j){
                int c = kh*32 + g*8 + j;
                Bx[kh][j] = *reinterpret_cast<const short*>(xb + (size_t)c*HWS + px);
            }
        // stage 1 (bias in acc init: D row = channel)
        f32x4 Dz[4], Df[4];
        #pragma unroll
        for (int ot=0; ot<4; ++ot){
            Dz[ot] = *(const f32x4*)(bz1 + ot*16 + g*4);
            Df[ot] = *(const f32x4*)(bf1 + ot*16 + g*4);
        }
        #pragma unroll
        for (int kh=0; kh<2; ++kh)
            #pragma unroll
            for (int ot=0; ot<4; ++ot){
                Dz[ot] = __builtin_amdgcn_mfma_f32_16x16x32_bf16(Az1[ot][kh], Bx[kh], Dz[ot], 0,0,0);
                Df[ot] = __builtin_amdgcn_mfma_f32_16x16x32_bf16(Af1[ot][kh], Bx[kh], Df[ot], 0,0,0);
            }
        #pragma unroll
        for (int ot=0; ot<4; ++ot)
            #pragma unroll
            for (int r=0; r<4; ++r){
                Dz[ot][r] = ftanh(Dz[ot][r]);
                Df[ot][r] = ftanh(Df[ot][r]);
            }
        // stage-2 B = stage-1 D (same lane, psi2 slots)
        bf16x8 Bz[2], Bf[2];
        #pragma unroll
        for (int kh=0; kh<2; ++kh)
            #pragma unroll
            for (int j=0; j<4; ++j){
                Bz[kh][j]   = (short)f2u(Dz[2*kh][j]);
                Bz[kh][4+j] = (short)f2u(Dz[2*kh+1][j]);
                Bf[kh][j]   = (short)f2u(Df[2*kh][j]);
                Bf[kh][4+j] = (short)f2u(Df[2*kh+1][j]);
            }
        f32x4 Ez[4], Ef[4];
        #pragma unroll
        for (int ot=0; ot<4; ++ot){
            Ez[ot] = *(const f32x4*)(bz2 + ot*16 + g*4);
            Ef[ot] = *(const f32x4*)(bf2 + ot*16 + g*4);
        }
        #pragma unroll
        for (int kh=0; kh<2; ++kh)
            #pragma unroll
            for (int ot=0; ot<4; ++ot){
                Ez[ot] = __builtin_amdgcn_mfma_f32_16x16x32_bf16(Az2[ot][kh], Bz[kh], Ez[ot], 0,0,0);
                Ef[ot] = __builtin_amdgcn_mfma_f32_16x16x32_bf16(Af2[ot][kh], Bf[kh], Ef[ot], 0,0,0);
            }
        #pragma unroll
        for (int ot=0; ot<4; ++ot)
            #pragma unroll
            for (int r=0; r<4; ++r){
                float Zv = ftanh(Ez[ot][r]);
                float Fv = fsig(Ef[ot][r]);
                *reinterpret_cast<unsigned short*>(vb + (size_t)(ot*16+g*4+r)*HWS + px)
                    = f2u((1.f - Fv)*Zv);
            }
    }
}

// ---------------------------------------------------------------- pconv (16->16, 3x3), 4 px/thread
__global__ __launch_bounds__(256) void k_pconv(
    const bf16* __restrict__ v, const float* __restrict__ w, bf16* __restrict__ x1)
{
    int gid = blockIdx.x*256 + threadIdx.x;       // thread = 4 px
    int b = gid >> 12;
    int sp4 = (gid & 4095) << 2;
    int y = sp4 >> 7, x0 = sp4 & 127;
    const bf16* vb = v + (size_t)b*CC*HWS;
    float acc[DCC][4];
    #pragma unroll
    for (int o=0;o<DCC;++o)
        #pragma unroll
        for (int i=0;i<4;++i) acc[o][i] = 0.f;

    #pragma unroll 1
    for (int ic=0; ic<DCC; ++ic){
        const bf16* ip = vb + (size_t)ic*HWS;
        float xv[3][6];
        #pragma unroll
        for (int ky=0;ky<3;++ky){
            int yy = y + ky - 1;
            if (yy >= 0 && yy < HH){
                const bf16* rp = ip + yy*WW + x0;
                ushort4v mv = *reinterpret_cast<const ushort4v*>(rp);
                xv[ky][1]=u2f(mv[0]); xv[ky][2]=u2f(mv[1]);
                xv[ky][3]=u2f(mv[2]); xv[ky][4]=u2f(mv[3]);
                xv[ky][0] = (x0>0)     ? b2f(rp[-1]) : 0.f;
                xv[ky][5] = (x0+4<WW)  ? b2f(rp[4])  : 0.f;
            } else {
                #pragma unroll
                for (int i=0;i<6;++i) xv[ky][i] = 0.f;
            }
        }
        #pragma unroll
        for (int o=0;o<DCC;++o){
            const float* wp = w + (size_t)(o*DCC+ic)*9;
            #pragma unroll
            for (int ky=0;ky<3;++ky){
                float w0 = wp[ky*3+0], w1 = wp[ky*3+1], w2 = wp[ky*3+2];
                #pragma unroll
                for (int i=0;i<4;++i)
                    acc[o][i] = fmaf(w0, xv[ky][i],
                                fmaf(w1, xv[ky][i+1],
                                fmaf(w2, xv[ky][i+2], acc[o][i])));
            }
        }
    }
    bf16* xo = x1 + (size_t)b*DCC*HWS + sp4;
    #pragma unroll
    for (int o=0;o<DCC;++o){
        ushort4v ov;
        #pragma unroll
        for (int i=0;i<4;++i) ov[i] = f2u(acc[o][i]);
        *reinterpret_cast<ushort4v*>(xo + (size_t)o*HWS) = ov;
    }
}

// ---------------------------------------------------------------- lin1 (64->256 + gelu), MFMA
__global__ __launch_bounds__(256,2) void k_lin1(
    const bf16* __restrict__ x1, const bf16* __restrict__ v,
    const float* __restrict__ w, const float* __restrict__ bias,
    bf16* __restrict__ h)
{
    const int t = threadIdx.x;
    const int lane = t & 63;
    const int wv = t >> 6;
    const int col = lane & 15;
    const int g = lane >> 4;
    const int blk = blockIdx.x;
    const int b = blk >> 5;
    const int sp0 = (blk & 31) << 9;

    // A[m=och][k=c] = w[c][och]  (w is [64][256])
    bf16x8 A[16][2];
    #pragma unroll
    for (int nt=0; nt<16; ++nt)
        #pragma unroll
        for (int kh=0; kh<2; ++kh){
            float4v lo, hi;
            #pragma unroll
            for (int j=0;j<4;++j){
                lo[j] = w[(kh*32 + g*8 + j)*256 + nt*16 + col];
                hi[j] = w[(kh*32 + g*8 + 4 + j)*256 + nt*16 + col];
            }
            A[nt][kh] = packf(lo, hi);
        }

    for (int it = wv; it < 32; it += 4){
        const int px = sp0 + it*16 + col;
        bf16x8 Bx[2];
        #pragma unroll
        for (int kh=0; kh<2; ++kh)
            #pragma unroll
            for (int j=0; j<8; ++j){
                int c = kh*32 + g*8 + j;
                const bf16* src = (c < DCC) ? x1 + ((size_t)b*DCC + c)*HWS
                                            : v  + ((size_t)b*CC  + c)*HWS;
                Bx[kh][j] = *reinterpret_cast<const short*>(src + px);
            }
        f32x4 D[16];
        #pragma unroll
        for (int nt=0; nt<16; ++nt)
            D[nt] = *(const f32x4*)(bias + nt*16 + g*4);
        #pragma unroll
        for (int kh=0; kh<2; ++kh)
            #pragma unroll
            for (int nt=0; nt<16; ++nt)
                D[nt] = __builtin_amdgcn_mfma_f32_16x16x32_bf16(A[nt][kh], Bx[kh], D[nt], 0,0,0);
        bf16* hb = h + (size_t)b*256*HWS + px;
        #pragma unroll
        for (int nt=0; nt<16; ++nt)
            #pragma unroll
            for (int r=0; r<4; ++r)
                *reinterpret_cast<unsigned short*>(hb + (size_t)(nt*16+g*4+r)*HWS)
                    = f2u(fgelu(D[nt][r]));
    }
}

// ---------------------------------------------------------------- dw conv + gelu + gate -> g (in-place over h2)
__global__ __launch_bounds__(256) void k_dwgate(
    const bf16* h, const float* __restrict__ dww,
    const float* __restrict__ dwb, bf16* gout)
{
    const int t   = threadIdx.x;
    const int bid = blockIdx.x;
    const int rg  = bid & 7;
    const int k   = __builtin_amdgcn_readfirstlane((bid >> 3) & 127);
    const int b   = __builtin_amdgcn_readfirstlane(bid >> 10);
    const int row = (rg << 4) + (t >> 4);
    const int x0  = (t & 15) << 3;

    const bf16* h1p = h + ((size_t)(b*256 + k))*HWS;
    float acc[8];
    #pragma unroll
    for (int i=0;i<8;++i) acc[i]=0.f;

    #pragma unroll
    for (int ky=0; ky<3; ++ky){
        int yy = row + ky - 1;
        if (yy < 0 || yy >= HH) continue;
        const bf16* rp = h1p + yy*WW + x0;
        ushort8 mv = *reinterpret_cast<const ushort8*>(rp);
        float m[8];
        #pragma unroll
        for (int i=0;i<8;++i) m[i] = u2f(mv[i]);
        float lft = (x0>0)    ? b2f(rp[-1]) : 0.f;
        float rgt = (x0+8<WW) ? b2f(rp[8])  : 0.f;
        float w0 = dww[k*9+ky*3+0], w1 = dww[k*9+ky*3+1], w2 = dww[k*9+ky*3+2];
        #pragma unroll
        for (int i=0;i<8;++i){
            float l = (i==0) ? lft : m[i-1];
            float r = (i==7) ? rgt : m[i+1];
            acc[i] = fmaf(w0, l, fmaf(w1, m[i], fmaf(w2, r, acc[i])));
        }
    }
    float bk = dwb[k];
    const size_t off2 = ((size_t)(b*256 + 128 + k))*HWS + row*WW + x0;
    ushort8 h2v = *reinterpret_cast<const ushort8*>(h + off2);
    ushort8 ov;
    #pragma unroll
    for (int i=0;i<8;++i){
        float h1 = fgelu(acc[i] + bk);
        ov[i] = f2u(h1 * u2f(h2v[i]));
    }
    *reinterpret_cast<ushort8*>(gout + off2) = ov;
}

// ---------------------------------------------------------------- lin2 (128->64) + residual, MFMA
__global__ __launch_bounds__(256,2) void k_lin2(
    const bf16* __restrict__ hg,     // g lives in planes 128..255 of h
    const float* __restrict__ w2, const float* __restrict__ b2v,
    const bf16* __restrict__ v,
    bf16* __restrict__ xout,
    const float* __restrict__ xinit,   // non-null on last layer
    bf16* __restrict__ xsum)           // may alias v
{
    const int t = threadIdx.x;
    const int lane = t & 63;
    const int wv = t >> 6;
    const int col = lane & 15;
    const int g = lane >> 4;
    const int blk = blockIdx.x;
    const int b = blk >> 5;
    const int sp0 = (blk & 31) << 9;

    // A[m=c][k] = w2[k][c]  (w2 is [128][64])
    bf16x8 A[4][4];
    #pragma unroll
    for (int ot=0; ot<4; ++ot)
        #pragma unroll
        for (int kh=0; kh<4; ++kh){
            float4v lo, hi;
            #pragma unroll
            for (int j=0;j<4;++j){
                lo[j] = w2[(kh*32 + g*8 + j)*64 + ot*16 + col];
                hi[j] = w2[(kh*32 + g*8 + 4 + j)*64 + ot*16 + col];
            }
            A[ot][kh] = packf(lo, hi);
        }
    const bf16* gb = hg + (size_t)(b*256 + 128)*HWS;

    for (int it = wv; it < 32; it += 4){
        const int px = sp0 + it*16 + col;
        bf16x8 Bg[4];
        #pragma unroll
        for (int kh=0; kh<4; ++kh)
            #pragma unroll
            for (int j=0; j<8; ++j){
                int k = kh*32 + g*8 + j;
                Bg[kh][j] = *reinterpret_cast<const short*>(gb + (size_t)k*HWS + px);
            }
        f32x4 D[4];
        #pragma unroll
        for (int ot=0; ot<4; ++ot)
            D[ot] = *(const f32x4*)(b2v + ot*16 + g*4);
        #pragma unroll
        for (int kh=0; kh<4; ++kh)
            #pragma unroll
            for (int ot=0; ot<4; ++ot)
                D[ot] = __builtin_amdgcn_mfma_f32_16x16x32_bf16(A[ot][kh], Bg[kh], D[ot], 0,0,0);
        #pragma unroll
        for (int ot=0; ot<4; ++ot)
            #pragma unroll
            for (int r=0; r<4; ++r){
                int ch = ot*16 + g*4 + r;
                size_t off = ((size_t)b*CC + ch)*HWS + px;
                float rr = D[ot][r] + b2f(v[off]);
                *reinterpret_cast<unsigned short*>(xout + off) = f2u(rr);
                if (xinit){
                    float s = rr + xinit[off];
                    *reinterpret_cast<unsigned short*>(xsum + off) = f2u(s);
                }
            }
    }
}

// ---------------------------------------------------------------- final conv (64->1, 3x3), 4 px/thread
__global__ __launch_bounds__(256) void k_final(
    const bf16* __restrict__ s, const float* __restrict__ w,
    const float* __restrict__ bias, float* __restrict__ out)
{
    int gid = blockIdx.x*256 + threadIdx.x;   // thread = 4 px
    int b = gid >> 12;
    int sp4 = (gid & 4095) << 2;
    int y = sp4 >> 7, x0 = sp4 & 127;
    const bf16* sb = s + (size_t)b*CC*HWS;
    float acc[4];
    #pragma unroll
    for (int i=0;i<4;++i) acc[i] = bias[0];

    #pragma unroll 1
    for (int c=0;c<CC;++c){
        const bf16* ip = sb + (size_t)c*HWS;
        const float* wp = w + (size_t)c*9;
        #pragma unroll
        for (int ky=0;ky<3;++ky){
            int yy = y + ky - 1;
            float xv[6];
            if (yy >= 0 && yy < HH){
                const bf16* rp = ip + yy*WW + x0;
                ushort4v mv = *reinterpret_cast<const ushort4v*>(rp);
                xv[1]=u2f(mv[0]); xv[2]=u2f(mv[1]); xv[3]=u2f(mv[2]); xv[4]=u2f(mv[3]);
                xv[0] = (x0>0)    ? b2f(rp[-1]) : 0.f;
                xv[5] = (x0+4<WW) ? b2f(rp[4])  : 0.f;
            } else {
                #pragma unroll
                for (int i=0;i<6;++i) xv[i] = 0.f;
            }
            float w0 = wp[ky*3+0], w1 = wp[ky*3+1], w2 = wp[ky*3+2];
            #pragma unroll
            for (int i=0;i<4;++i)
                acc[i] = fmaf(w0, xv[i],
                         fmaf(w1, xv[i+1],
                         fmaf(w2, xv[i+2], acc[i])));
        }
    }
    float4v ov; ov.x=acc[0]; ov.y=acc[1]; ov.z=acc[2]; ov.w=acc[3];
    *reinterpret_cast<float4v*>(out + (size_t)gid*4) = ov;
}

// ---------------------------------------------------------------- launch
extern "C" void kernel_launch(void* const* d_in, const int* in_sizes, int n_in,
                              void* d_out, int out_size, void* d_ws, size_t ws_size,
                              hipStream_t stream)
{
    const float* x    = (const float*)d_in[0];
    const float* wz1  = (const float*)d_in[1];
    const float* bz1  = (const float*)d_in[2];
    const float* wz2  = (const float*)d_in[3];
    const float* bz2  = (const float*)d_in[4];
    const float* wf1  = (const float*)d_in[5];
    const float* bf1  = (const float*)d_in[6];
    const float* wf2  = (const float*)d_in[7];
    const float* bf2  = (const float*)d_in[8];
    const float* pw   = (const float*)d_in[9];
    const float* l1w  = (const float*)d_in[10];
    const float* l1b  = (const float*)d_in[11];
    const float* dww  = (const float*)d_in[12];
    const float* dwb  = (const float*)d_in[13];
    const float* l2w  = (const float*)d_in[14];
    const float* l2b  = (const float*)d_in[15];
    const float* ow   = (const float*)d_in[16];
    const float* obb  = (const float*)d_in[17];

    char* ws = (char*)d_ws;
    bf16* xc = (bf16*)(ws);                       // 33,554,432 B
    bf16* v  = (bf16*)(ws + 33554432);            // 33,554,432 B
    bf16* x1 = (bf16*)(ws + 67108864);            //  8,388,608 B
    bf16* h  = (bf16*)(ws + 75497472);            // 134,217,728 B (g aliases planes 128..255)

    k_convert<<<(NPIX*CC)/(256*8), 256, 0, stream>>>(x, xc, NPIX*CC);
    for (int l=0;l<3;++l){
        k_gate <<<512, 256, 0, stream>>>(xc,
                wz1 + l*CC*CC, bz1 + l*CC, wz2 + l*CC*CC, bz2 + l*CC,
                wf1 + l*CC*CC, bf1 + l*CC, wf2 + l*CC*CC, bf2 + l*CC, v);
        k_pconv<<<NPIX/(256*4), 256, 0, stream>>>(v, pw + l*DCC*DCC*9, x1);
        k_lin1 <<<512, 256, 0, stream>>>(x1, v, l1w + l*CC*256, l1b + l*256, h);
        k_dwgate<<<BB*HIDN*(HH/16), 256, 0, stream>>>(h, dww + l*HIDN*9, dwb + l*HIDN, h);
        k_lin2 <<<512, 256, 0, stream>>>(h, l2w + l*HIDN*CC, l2b + l*CC, v, xc,
                (l==2) ? x : nullptr, v);
    }
    k_final<<<NPIX/(256*4), 256, 0, stream>>>(v, ow, obb, (float*)d_out);
}